// Round 10
// baseline (266.817 us; speedup 1.0000x reference)
//
#include <hip/hip_runtime.h>

#define N_E   1024
#define EDIM  256
#define BB    16
#define TT    1024
#define NROW  (BB*TT)        /* 16384 */
#define NCOL  1025
#define NPAD  1152           /* 36 col-blocks of 32 */
#define PERS  (0.1f/1024.0f)
#define EPSC  (1e-6f/1024.0f)

/* d_out layout (float32): z_q [0,4194304) | loss 4194304 | ind [4194305,+16384) | v 4210689 */
#define OUT_LOSS 4194304
#define OUT_IDX  4194305
#define OUT_V    4210689

/* ws layout (bytes) */
#define WS_ZB   0ull                               /* 16384*256*2  = 8388608  */
#define WS_BBF  8388608ull                         /* 1152*256*2   = 589824   */
#define WS_BSQ  8978432ull                         /* 1152*4       = 4608     */
#define WS_E    8983552ull                         /* 16384*1152*4 = 75497472 */
#define WS_IND  84481024ull                        /* 16384*4                 */
#define WS_PART 84546560ull                        /* 16384*4                 */

/* e layout: e5[b][cb][t][32], cb = col>>5 (36 blocks), t = row within batch.
   Rationale (r0-r8): row-major [row][1152] put every window row on a fresh
   4KB page -> per-wave loads drained serially (~250-400cy each,
   translation-serialized), invariant across VGPR loads, LDS-DMA, depth.
   Here a 2-row x 32-col window piece is ONE contiguous 256B load and 16
   consecutive rows share a page.                                           */
#define CBSTR 32768u                       /* floats per (b,cb) region: 1024*32 */

typedef __attribute__((ext_vector_type(8))) short short8;
typedef __attribute__((ext_vector_type(4))) float floatx4;

__device__ __forceinline__ unsigned short f2bf(float f) {
    unsigned int u = __float_as_uint(f);
    u = (u + 0x7fffu + ((u >> 16) & 1u)) >> 16;   /* RNE */
    return (unsigned short)u;
}

__device__ __forceinline__ float gload_f32(const float* p) {
    float r;
    asm volatile("global_load_dword %0, %1, off" : "=v"(r) : "v"(p));
    return r;
}

/* ---------------- K0: convert z/book -> bf16, compute bsq (fp32) ---------------- */
__global__ __launch_bounds__(256) void k0_prep(const float* __restrict__ z,
                                               const float* __restrict__ book,
                                               unsigned short* __restrict__ zb,
                                               unsigned short* __restrict__ bb,
                                               float* __restrict__ bsq) {
    int bx = blockIdx.x, tid = threadIdx.x;
    if (bx < 4096) {                     /* z: 4096 blocks * 256 thr * 4 floats */
        float4 v = ((const float4*)z)[bx * 256 + tid];
        size_t o = ((size_t)bx * 256 + tid) * 4;
        zb[o + 0] = f2bf(v.x); zb[o + 1] = f2bf(v.y);
        zb[o + 2] = f2bf(v.z); zb[o + 3] = f2bf(v.w);
    } else {                             /* book rows, padded to 1152 with zeros */
        int row = bx - 4096;             /* 0..1151 */
        float v = (row < NCOL) ? book[(size_t)row * EDIM + tid] : 0.0f;
        bb[(size_t)row * EDIM + tid] = f2bf(v);
        __shared__ float sd[256];
        sd[tid] = v * v;
        __syncthreads();
        for (int s = 128; s > 0; s >>= 1) { if (tid < s) sd[tid] += sd[tid + s]; __syncthreads(); }
        if (tid == 0) bsq[row] = sd[0];
    }
}

/* ---------------- K1: e[r][n] = bsq[n] - 2*dot(z[r],book[n]); blocked store ---- */
__global__ __launch_bounds__(256) void k1_gemm(const unsigned short* __restrict__ zb,
                                               const unsigned short* __restrict__ bb,
                                               const float* __restrict__ bsq,
                                               float* __restrict__ e) {
    int tid = threadIdx.x;
    int lane = tid & 63, w = tid >> 6;
    int mBase = blockIdx.x * 128 + (w >> 1) * 64;
    int nBase = blockIdx.y * 128 + (w & 1) * 64;
    int r = lane & 15, q = lane >> 4;

    floatx4 acc[4][4];
    #pragma unroll
    for (int i = 0; i < 4; i++)
        #pragma unroll
        for (int j = 0; j < 4; j++) acc[i][j] = (floatx4){0.f, 0.f, 0.f, 0.f};

    const short8* A = (const short8*)zb;   /* row stride 256 bf16 = 32 short8 */
    const short8* Bm = (const short8*)bb;

    #pragma unroll
    for (int ks = 0; ks < 8; ks++) {
        int k8 = ks * 4 + q;
        short8 a[4], b[4];
        #pragma unroll
        for (int i = 0; i < 4; i++) a[i] = A[(size_t)(mBase + i * 16 + r) * 32 + k8];
        #pragma unroll
        for (int j = 0; j < 4; j++) b[j] = Bm[(size_t)(nBase + j * 16 + r) * 32 + k8];
        #pragma unroll
        for (int i = 0; i < 4; i++)
            #pragma unroll
            for (int j = 0; j < 4; j++)
                acc[i][j] = __builtin_amdgcn_mfma_f32_16x16x32_bf16(a[i], b[j], acc[i][j], 0, 0, 0);
    }

    float bsql[4];
    #pragma unroll
    for (int j = 0; j < 4; j++) bsql[j] = bsq[nBase + j * 16 + r];

    #pragma unroll
    for (int i = 0; i < 4; i++)
        #pragma unroll
        for (int rr = 0; rr < 4; rr++) {
            int m = mBase + i * 16 + q * 4 + rr;
            float* ebb = e + ((size_t)(m >> 10) * 36) * CBSTR + (size_t)(m & 1023) * 32;
            #pragma unroll
            for (int j = 0; j < 4; j++) {
                int cb = (nBase >> 5) + (j >> 1);
                int cl = ((j & 1) << 4) + r;
                ebb[(size_t)cb * CBSTR + cl] = fmaf(-2.0f, acc[i][j][rr], bsql[j]);
            }
        }
}

/* ---------------- K2: serial neighbor scan, one block per batch row ------------
   Phase A (4 waves): fp32 argmin of d[b,0,:] reference-style.
   Phase B (wave 0): integer-scan, depth-3, 6-row chunks, 64-col window as TWO
   32-aligned subwindows (col blocks cb, cb+1). Per chunk: 6 fully-contiguous
   256B loads (2 rows x 32 cols each), page-dense in the blocked layout.
   FIXES vs r9 (failed, absmax 56):
   (1) base rotation is now 3-deep (b0<-b1<-b2<-cbI) matching the depth-3
       pipeline. r9 kept r8's 4-deep rotation: from iter 2 the q-compute and
       from iter 3 the chain used the PREVIOUS chunk's base -> wrong readlane
       whenever ind crossed a 32-boundary between snapshots.
   (2) no pair clamp on load rows: the (1023,1024) pair loads naturally, so
       real row 1023's q sits at its expected parity. Phantom rows >1023 read
       in-bounds garbage from the next col-block (max addr (cb+1)*CBSTR +
       1043*32+63 < 36*CBSTR, cb<=30) consumed only by store-guarded steps.
   Drift bound: base snapshot at iter c serves chunk c+3; rel <= 31 (snapshot)
   + 23 (3 chunks + 5 rows) = 54 < 64; at the 960-clamp rel <= 63 with col
   1023 = w1 lane 31 = cap lane (q forced 0 = reference ind=1023 behavior);
   w0 is never capped (cols <= 991). w0 lane31's col+1 neighbor comes from
   w1 lane0 via shfl_up(A1,31,32).
   vmcnt ledger: per iter [6 loads][chain][1 store][vmcnt(15)][qcomp]; ops
   newer than chunk c+1's loads at the wait: s+6L+s+6L+s = 15. Prologue
   [6L+s]x3 = 21 ops, vmcnt(15) retires chunk 0. Max outstanding 22 <= 63.  */

#define GCH 6

#define DECLW float A00_0, A00_1, A00_2, A01_0, A01_1, A01_2, \
                    A10_0, A10_1, A10_2, A11_0, A11_1, A11_2, \
                    A20_0, A20_1, A20_2, A21_0, A21_1, A21_2; \
              int q0_0, q0_1, q0_2, q1_0, q1_1, q1_2;

#define LD6(S) { \
    const float* _pb = eb5 + (size_t)(cbI >> 5) * CBSTR + lane; \
    { size_t _o = (size_t)(ti)     * 32; \
      A##S##0_0 = gload_f32(_pb + _o); A##S##1_0 = gload_f32(_pb + CBSTR + _o); } \
    { size_t _o = (size_t)(ti + 2) * 32; \
      A##S##0_1 = gload_f32(_pb + _o); A##S##1_1 = gload_f32(_pb + CBSTR + _o); } \
    { size_t _o = (size_t)(ti + 4) * 32; \
      A##S##0_2 = gload_f32(_pb + _o); A##S##1_2 = gload_f32(_pb + CBSTR + _o); } }

#define QCW(S,k) { \
    float _bv0 = __shfl_down(A##S##0_##k, 1, 32); \
    float _bx  = __shfl_up(A##S##1_##k, 31, 32);  /* lane h+31 <- A1 lane h+0 */ \
    _bv0 = (_cl == 31) ? _bx : _bv0; \
    q0_##k = (int)((_bv0 - A##S##0_##k) * QS); \
    float _bv1 = __shfl_down(A##S##1_##k, 1, 32); \
    int _q1 = (int)((_bv1 - A##S##1_##k) * QS); \
    q1_##k = _cap1 ? 0 : _q1; }
#define QCSET(S) QCW(S,0) QCW(S,1) QCW(S,2)

/* chain step: row j, pair k=j>>1, parity h=(j&1)*32; rel selects w0/w1 */
#define CHS(j,k,h) { int _rel = ind - b0; \
    int _la = h + (_rel & 31); \
    int _qa = __builtin_amdgcn_readlane(q0_##k, _la); \
    int _qb = __builtin_amdgcn_readlane(q1_##k, _la); \
    int _qv = _rel < 32 ? _qa : _qb; \
    bool _stay = (kk <= _qv); \
    int _ip1 = ind + 1; _ip1 = _ip1 < 1023 ? _ip1 : 1023; \
    ind = _stay ? ind : _ip1; \
    kk  = _stay ? kk + 1 : 0; \
    packed = (lane == j) ? ind : packed; }
#define CHAIN6 CHS(0,0,0) CHS(1,0,32) CHS(2,1,0) CHS(3,1,32) CHS(4,2,0) CHS(5,2,32)

#define ITERX(S, SQ) { \
    int cbI = ind < 960 ? (ind & ~31) : 960;   /* base, chunk c+3 */ \
    { int ti = t + 18; LD6(S) } \
    __builtin_amdgcn_sched_barrier(0); \
    int packed = 0; \
    CHAIN6 \
    if (lane < GCH && t + lane < 1024) wind[ibase + t + lane] = packed; \
    __builtin_amdgcn_sched_barrier(0); \
    asm volatile("s_waitcnt vmcnt(15)" ::: "memory"); /* chunk c+1 landed */ \
    __builtin_amdgcn_sched_barrier(0); \
    { bool _cap1 = (b1 + 32 + _cl == 1023); QCSET(SQ) } \
    __builtin_amdgcn_sched_barrier(0); \
    b0 = b1; b1 = b2; b2 = cbI; \
    t += GCH; }

__global__ __launch_bounds__(256, 1) void k2_scan(const float* __restrict__ z,
                                                  const float* __restrict__ book,
                                                  const float* __restrict__ bsq,
                                                  const float* __restrict__ e,
                                                  int* __restrict__ wind) {
    __shared__ float sb[4]; __shared__ int si[4];

    int b = blockIdx.x, tid = threadIdx.x;
    int lane = tid & 63, w = tid >> 6;

    const float4* zr = (const float4*)(z + (size_t)b * TT * EDIM);  /* t=0 row */
    float4 zv = zr[lane];
    float s = zv.x * zv.x + zv.y * zv.y + zv.z * zv.z + zv.w * zv.w;
    #pragma unroll
    for (int off = 32; off; off >>= 1) s += __shfl_xor(s, off, 64);
    float zsq = s;

    float best = 3.4e38f; int bidx = 0;
    for (int wi = w; wi < 17; wi += 4) {
        int n = wi * 64 + lane;
        if (n < NCOL) {
            const float4* br = (const float4*)(book + (size_t)n * EDIM);
            float c0 = 0.f, c1 = 0.f, c2 = 0.f, c3 = 0.f;
            #pragma unroll 8
            for (int k = 0; k < 64; k++) {
                float4 bo = br[k]; float4 za = zr[k];
                c0 = fmaf(za.x, bo.x, c0); c1 = fmaf(za.y, bo.y, c1);
                c2 = fmaf(za.z, bo.z, c2); c3 = fmaf(za.w, bo.w, c3);
            }
            float cr = (c0 + c1) + (c2 + c3);
            float d0 = (zsq + bsq[n]) - 2.0f * cr;     /* reference-style formation */
            if (d0 < best || (d0 == best && n < bidx)) { best = d0; bidx = n; }
        }
    }
    #pragma unroll
    for (int off = 32; off; off >>= 1) {
        float ob = __shfl_xor(best, off, 64);
        int   oi = __shfl_xor(bidx, off, 64);
        if (ob < best || (ob == best && oi < bidx)) { best = ob; bidx = oi; }
    }
    if (lane == 0) { sb[w] = best; si[w] = bidx; }
    __syncthreads();
    if (w != 0) return;

    best = sb[0]; bidx = si[0];
    for (int i = 1; i < 4; i++) {
        float vv = sb[i]; int ii = si[i];
        if (vv < best || (vv == best && ii < bidx)) { best = vv; bidx = ii; }
    }

    int ind = min(bidx, N_E - 1);
    int kk = 0;                              /* coe = kk * PERS */
    size_t ibase = (size_t)b * TT;

    const float* eb5 = e + ((size_t)b * 36) * CBSTR;
    const float QS = 1.0f / PERS;            /* 10240 */

    int _cl = lane & 31;                     /* col within subwindow */

    DECLW

    /* drain phase-A VMEM so the vmcnt ledger starts clean */
    asm volatile("s_waitcnt vmcnt(0)" ::: "memory");
    __builtin_amdgcn_sched_barrier(0);

    int B0 = ind < 960 ? (ind & ~31) : 960;
    int b0 = B0, b1 = B0, b2 = B0;

    /* prologue: chunks 0..2 (rows 1-6, 7-12, 13-18), each [6 loads + 1
       volatile wind store] establishing the uniform vmcnt ledger */
    { int cbI = B0; { int ti = 1;  LD6(0) } }
    if (lane == 0) *(volatile int*)(wind + ibase) = ind;
    { int cbI = B0; { int ti = 7;  LD6(1) } }
    if (lane == 0) *(volatile int*)(wind + ibase) = ind;
    { int cbI = B0; { int ti = 13; LD6(2) } }
    if (lane == 0) *(volatile int*)(wind + ibase) = ind;
    __builtin_amdgcn_sched_barrier(0);
    asm volatile("s_waitcnt vmcnt(15)" ::: "memory");  /* chunk 0 landed */
    __builtin_amdgcn_sched_barrier(0);
    {   /* q for chunk 0 */
        bool _cap1 = (b0 + 32 + _cl == 1023);
        QCSET(0)
    }
    __builtin_amdgcn_sched_barrier(0);

    int t = 1;
    #pragma unroll 1
    for (int cc = 0; cc < 57; cc++) {        /* 171 iters: rows 1..1026 (guarded) */
        ITERX(0, 1)
        ITERX(1, 2)
        ITERX(2, 0)
    }
}

/* ---------------- K3: per-row hinge-loss partial + z_q gather + idx emit ------ */
__global__ __launch_bounds__(256) void k3_loss_zq(const float* __restrict__ e,
                                                  const int* __restrict__ wind,
                                                  const float* __restrict__ book,
                                                  float* __restrict__ part,
                                                  float* __restrict__ out) {
    int rIdx = blockIdx.x, tid = threadIdx.x;
    int ind = wind[rIdx];
    const float* er5 = e + ((size_t)(rIdx >> 10) * 36) * CBSTR + (size_t)(rIdx & 1023) * 32;
    float eind = er5[(size_t)(ind >> 5) * CBSTR + (ind & 31)];
    float p = 0.0f;
    for (int n = tid; n < NCOL; n += 256) {
        float v = eind - er5[(size_t)(n >> 5) * CBSTR + (n & 31)] + EPSC;
        p += v > 0.0f ? v : 0.0f;
    }
    __shared__ float sd[256];
    sd[tid] = p; __syncthreads();
    for (int s = 128; s > 0; s >>= 1) { if (tid < s) sd[tid] += sd[tid + s]; __syncthreads(); }
    if (tid == 0) { part[rIdx] = sd[0]; out[OUT_IDX + rIdx] = (float)ind; }
    out[(size_t)rIdx * 256 + tid] = book[(size_t)ind * EDIM + tid];   /* z_q */
}

/* ---------------- K4: final loss reduce + v ---------------- */
__global__ __launch_bounds__(256) void k4_final(const float* __restrict__ part,
                                                const int* __restrict__ wind,
                                                float* __restrict__ out) {
    int tid = threadIdx.x;
    float s = 0.0f;
    for (int i = tid; i < NROW; i += 256) s += part[i];
    __shared__ float sd[256];
    sd[tid] = s; __syncthreads();
    for (int st = 128; st > 0; st >>= 1) { if (tid < st) sd[tid] += sd[tid + st]; __syncthreads(); }
    if (tid == 0) {
        int mn = wind[0], mx = wind[TT - 1];
        for (int b = 1; b < BB; b++) {
            mn = min(mn, wind[(size_t)b * TT]);
            mx = max(mx, wind[(size_t)b * TT + TT - 1]);
        }
        out[OUT_LOSS] = 1.25f * sd[0] / ((float)NROW * (float)NCOL);
        out[OUT_V] = (float)(mx - mn);
    }
}

extern "C" void kernel_launch(void* const* d_in, const int* in_sizes, int n_in,
                              void* d_out, int out_size, void* d_ws, size_t ws_size,
                              hipStream_t stream) {
    const float* z    = (const float*)d_in[0];
    const float* book = (const float*)d_in[1];
    char* ws = (char*)d_ws;
    unsigned short* zb = (unsigned short*)(ws + WS_ZB);
    unsigned short* bb = (unsigned short*)(ws + WS_BBF);
    float* bsq  = (float*)(ws + WS_BSQ);
    float* e    = (float*)(ws + WS_E);
    int*   wind = (int*)(ws + WS_IND);
    float* part = (float*)(ws + WS_PART);
    float* out  = (float*)d_out;

    hipLaunchKernelGGL(k0_prep,    dim3(4096 + 1152), dim3(256), 0, stream, z, book, zb, bb, bsq);
    hipLaunchKernelGGL(k1_gemm,    dim3(128, 9),      dim3(256), 0, stream, zb, bb, bsq, e);
    hipLaunchKernelGGL(k2_scan,    dim3(16),          dim3(256), 0, stream, z, book, bsq, e, wind);
    hipLaunchKernelGGL(k3_loss_zq, dim3(16384),       dim3(256), 0, stream, e, wind, book, part, out);
    hipLaunchKernelGGL(k4_final,   dim3(1),           dim3(256), 0, stream, part, wind, out);
}

// Round 11
// 262.514 us; speedup vs baseline: 1.0164x; 1.0164x over previous
//
#include <hip/hip_runtime.h>

#define N_E   1024
#define EDIM  256
#define BB    16
#define TT    1024
#define NROW  (BB*TT)        /* 16384 */
#define NCOL  1025
#define NPAD  1152           /* row-major e row stride (r8 proven layout) */
#define PERS  (0.1f/1024.0f)
#define EPSC  (1e-6f/1024.0f)

/* d_out layout (float32): z_q [0,4194304) | loss 4194304 | ind [4194305,+16384) | v 4210689 */
#define OUT_LOSS 4194304
#define OUT_IDX  4194305
#define OUT_V    4210689

/* ws layout (bytes) */
#define WS_ZB   0ull                               /* 16384*256*2  = 8388608  */
#define WS_BBF  8388608ull                         /* 1152*256*2   = 589824   */
#define WS_BSQ  8978432ull                         /* 1152*4       = 4608     */
#define WS_E    8983552ull                         /* 16384*1152*4 = 75497472 */
#define WS_IND  84481024ull                        /* 16384*4                 */
#define WS_PART 84546560ull                        /* 16384*4                 */

typedef __attribute__((ext_vector_type(8))) short short8;
typedef __attribute__((ext_vector_type(4))) float floatx4;

__device__ __forceinline__ unsigned short f2bf(float f) {
    unsigned int u = __float_as_uint(f);
    u = (u + 0x7fffu + ((u >> 16) & 1u)) >> 16;   /* RNE */
    return (unsigned short)u;
}

__device__ __forceinline__ float gload_f32(const float* p) {
    float r;
    asm volatile("global_load_dword %0, %1, off" : "=v"(r) : "v"(p));
    return r;
}

/* ---------------- K0: convert z/book -> bf16, compute bsq (fp32) ---------------- */
__global__ __launch_bounds__(256) void k0_prep(const float* __restrict__ z,
                                               const float* __restrict__ book,
                                               unsigned short* __restrict__ zb,
                                               unsigned short* __restrict__ bb,
                                               float* __restrict__ bsq) {
    int bx = blockIdx.x, tid = threadIdx.x;
    if (bx < 4096) {                     /* z: 4096 blocks * 256 thr * 4 floats */
        float4 v = ((const float4*)z)[bx * 256 + tid];
        size_t o = ((size_t)bx * 256 + tid) * 4;
        zb[o + 0] = f2bf(v.x); zb[o + 1] = f2bf(v.y);
        zb[o + 2] = f2bf(v.z); zb[o + 3] = f2bf(v.w);
    } else {                             /* book rows, padded to 1152 with zeros */
        int row = bx - 4096;             /* 0..1151 */
        float v = (row < NCOL) ? book[(size_t)row * EDIM + tid] : 0.0f;
        bb[(size_t)row * EDIM + tid] = f2bf(v);
        __shared__ float sd[256];
        sd[tid] = v * v;
        __syncthreads();
        for (int s = 128; s > 0; s >>= 1) { if (tid < s) sd[tid] += sd[tid + s]; __syncthreads(); }
        if (tid == 0) bsq[row] = sd[0];
    }
}

/* ---------------- K1: e[r][n] = bsq[n] - 2 * dot(z[r], book[n])  (bf16 MFMA) ---- */
__global__ __launch_bounds__(256) void k1_gemm(const unsigned short* __restrict__ zb,
                                               const unsigned short* __restrict__ bb,
                                               const float* __restrict__ bsq,
                                               float* __restrict__ e) {
    int tid = threadIdx.x;
    int lane = tid & 63, w = tid >> 6;
    int mBase = blockIdx.x * 128 + (w >> 1) * 64;
    int nBase = blockIdx.y * 128 + (w & 1) * 64;
    int r = lane & 15, q = lane >> 4;

    floatx4 acc[4][4];
    #pragma unroll
    for (int i = 0; i < 4; i++)
        #pragma unroll
        for (int j = 0; j < 4; j++) acc[i][j] = (floatx4){0.f, 0.f, 0.f, 0.f};

    const short8* A = (const short8*)zb;   /* row stride 256 bf16 = 32 short8 */
    const short8* Bm = (const short8*)bb;

    #pragma unroll
    for (int ks = 0; ks < 8; ks++) {
        int k8 = ks * 4 + q;
        short8 a[4], b[4];
        #pragma unroll
        for (int i = 0; i < 4; i++) a[i] = A[(size_t)(mBase + i * 16 + r) * 32 + k8];
        #pragma unroll
        for (int j = 0; j < 4; j++) b[j] = Bm[(size_t)(nBase + j * 16 + r) * 32 + k8];
        #pragma unroll
        for (int i = 0; i < 4; i++)
            #pragma unroll
            for (int j = 0; j < 4; j++)
                acc[i][j] = __builtin_amdgcn_mfma_f32_16x16x32_bf16(a[i], b[j], acc[i][j], 0, 0, 0);
    }

    float bsql[4];
    #pragma unroll
    for (int j = 0; j < 4; j++) bsql[j] = bsq[nBase + j * 16 + r];

    #pragma unroll
    for (int i = 0; i < 4; i++)
        #pragma unroll
        for (int rr = 0; rr < 4; rr++) {
            int m = mBase + i * 16 + q * 4 + rr;
            float* erow = e + (size_t)m * NPAD;
            #pragma unroll
            for (int j = 0; j < 4; j++)
                erow[nBase + j * 16 + r] = fmaf(-2.0f, acc[i][j][rr], bsql[j]);
        }
}

/* ---------------- K2: serial neighbor scan, one block per batch row ------------
   512 threads. Phase A (8 waves): fp32 argmin of d[b,0,:].
   Phase B: producer-consumer. Wave 0 = SCANNER, waves 1-7 = FETCHERS.
   Why (r0-r10 post-mortem): one wave completes L1-missing loads at ~130cy
   per 128B line SERIALLY -- invariant across VGPR loads, LDS-DMA, pipeline
   depth, contiguity, page density. The only lever left: more waves fetching.
   Protocol (chunk = 6 rows, ring of 8 slots, full-value flags, no ABA):
     scanner after chunk c publishes sbase[(c+4)&7] then sready=c+4
       (lgkmcnt(0) between data and flag; lane 0 single writer);
     fetcher (chunk c = w-1 mod 7): poll sready==c, load 6 rows
       A=e[row][base+lane] (one 256B load/row, row-major), q = cap?0:
       trunc((shfl_down(A,1)-A)*QS)  [bit-identical to r8's formula],
       ds_write ringq[slot], lgkmcnt(0), dflag=c;
     scanner: poll dflag==c, 6 LDS reads, 6-step readlane chain (rel vs b0,
       4-deep base rotation -- r9 lesson), guarded wind store.
   Drift: base published after chunk c-4 -> rel <= 24 unclamped; at the 960
   clamp rel <= 63 with col 1023 = lane 63 = cap lane (q forced 0 = exact
   reference behavior at ind=1023); lane 63's shfl garbage is consumed only
   when capped. Rows clamped to 1023 for phantom tail (store-guarded).
   Ring WAR safe: fetcher c+8 starts only after scanner finished c+4 > c.   */

#define NCH 171
#define DLA 4

#define CHS1(j) { int _rel = ind - b0; \
    int _qv = __builtin_amdgcn_readlane(q_##j, _rel); \
    bool _stay = (kk <= _qv); \
    int _ip1 = ind + 1; _ip1 = _ip1 < 1023 ? _ip1 : 1023; \
    ind = _stay ? ind : _ip1; \
    kk  = _stay ? kk + 1 : 0; \
    packed = (lane == j) ? ind : packed; }

__global__ __launch_bounds__(512, 1) void k2_scan(const float* __restrict__ z,
                                                  const float* __restrict__ book,
                                                  const float* __restrict__ bsq,
                                                  const float* __restrict__ e,
                                                  int* __restrict__ wind) {
    __shared__ float sb[8]; __shared__ int si[8];
    __shared__ int ringq[8][6][64];      /* 12288 B */
    __shared__ int dflag[8];
    __shared__ int sready[8];
    __shared__ int sbase[8];

    int b = blockIdx.x, tid = threadIdx.x;
    int lane = tid & 63, w = tid >> 6;

    if (tid < 8) { dflag[tid] = -1; sready[tid] = -1; }

    const float4* zr = (const float4*)(z + (size_t)b * TT * EDIM);  /* t=0 row */
    float4 zv = zr[lane];
    float s = zv.x * zv.x + zv.y * zv.y + zv.z * zv.z + zv.w * zv.w;
    #pragma unroll
    for (int off = 32; off; off >>= 1) s += __shfl_xor(s, off, 64);
    float zsq = s;

    float best = 3.4e38f; int bidx = 0;
    for (int wi = w; wi < 17; wi += 8) {
        int n = wi * 64 + lane;
        if (n < NCOL) {
            const float4* br = (const float4*)(book + (size_t)n * EDIM);
            float c0 = 0.f, c1 = 0.f, c2 = 0.f, c3 = 0.f;
            #pragma unroll 8
            for (int k = 0; k < 64; k++) {
                float4 bo = br[k]; float4 za = zr[k];
                c0 = fmaf(za.x, bo.x, c0); c1 = fmaf(za.y, bo.y, c1);
                c2 = fmaf(za.z, bo.z, c2); c3 = fmaf(za.w, bo.w, c3);
            }
            float cr = (c0 + c1) + (c2 + c3);
            float d0 = (zsq + bsq[n]) - 2.0f * cr;     /* reference-style formation */
            if (d0 < best || (d0 == best && n < bidx)) { best = d0; bidx = n; }
        }
    }
    #pragma unroll
    for (int off = 32; off; off >>= 1) {
        float ob = __shfl_xor(best, off, 64);
        int   oi = __shfl_xor(bidx, off, 64);
        if (ob < best || (ob == best && oi < bidx)) { best = ob; bidx = oi; }
    }
    if (lane == 0) { sb[w] = best; si[w] = bidx; }
    __syncthreads();

    const float* eb = e + (size_t)b * TT * NPAD;
    const float QS = 1.0f / PERS;            /* 10240 */

    if (w != 0) {
        /* ---------------- FETCHER: chunks c == w-1 (mod 7) ---------------- */
        for (int c = w - 1; c < NCH; c += 7) {
            int slot = c & 7;
            while (*(volatile int*)&sready[slot] != c) {}
            asm volatile("" ::: "memory");
            int base = *(volatile int*)&sbase[slot];
            int t0 = 1 + 6 * c;
            const float* pw = eb + base + lane;
            float A_0, A_1, A_2, A_3, A_4, A_5;
            { int tr = t0 + 0; tr = tr < 1024 ? tr : 1023; A_0 = gload_f32(pw + (size_t)tr * NPAD); }
            { int tr = t0 + 1; tr = tr < 1024 ? tr : 1023; A_1 = gload_f32(pw + (size_t)tr * NPAD); }
            { int tr = t0 + 2; tr = tr < 1024 ? tr : 1023; A_2 = gload_f32(pw + (size_t)tr * NPAD); }
            { int tr = t0 + 3; tr = tr < 1024 ? tr : 1023; A_3 = gload_f32(pw + (size_t)tr * NPAD); }
            { int tr = t0 + 4; tr = tr < 1024 ? tr : 1023; A_4 = gload_f32(pw + (size_t)tr * NPAD); }
            { int tr = t0 + 5; tr = tr < 1024 ? tr : 1023; A_5 = gload_f32(pw + (size_t)tr * NPAD); }
            asm volatile("s_waitcnt vmcnt(0)" ::: "memory");
            __builtin_amdgcn_sched_barrier(0);
            bool cap = (base + lane == 1023);
            ringq[slot][0][lane] = cap ? 0 : (int)((__shfl_down(A_0, 1, 64) - A_0) * QS);
            ringq[slot][1][lane] = cap ? 0 : (int)((__shfl_down(A_1, 1, 64) - A_1) * QS);
            ringq[slot][2][lane] = cap ? 0 : (int)((__shfl_down(A_2, 1, 64) - A_2) * QS);
            ringq[slot][3][lane] = cap ? 0 : (int)((__shfl_down(A_3, 1, 64) - A_3) * QS);
            ringq[slot][4][lane] = cap ? 0 : (int)((__shfl_down(A_4, 1, 64) - A_4) * QS);
            ringq[slot][5][lane] = cap ? 0 : (int)((__shfl_down(A_5, 1, 64) - A_5) * QS);
            asm volatile("s_waitcnt lgkmcnt(0)" ::: "memory");
            if (lane == 0) *(volatile int*)&dflag[slot] = c;
        }
        return;
    }

    /* ---------------- SCANNER: wave 0 ---------------- */
    best = sb[0]; bidx = si[0];
    for (int i = 1; i < 8; i++) {
        float vv = sb[i]; int ii = si[i];
        if (vv < best || (vv == best && ii < bidx)) { best = vv; bidx = ii; }
    }

    int ind = min(bidx, N_E - 1);
    int kk = 0;                              /* coe = kk * PERS */
    size_t ibase = (size_t)b * TT;
    if (lane == 0) wind[ibase] = ind;

    int B0 = ind < 960 ? ind : 960;
    int b0 = B0, b1 = B0, b2 = B0, b3 = B0;

    /* publish bases for chunks 0..3 */
    if (lane == 0) { sbase[0] = B0; sbase[1] = B0; sbase[2] = B0; sbase[3] = B0; }
    asm volatile("s_waitcnt lgkmcnt(0)" ::: "memory");
    if (lane == 0) {
        *(volatile int*)&sready[0] = 0;
        *(volatile int*)&sready[1] = 1;
        *(volatile int*)&sready[2] = 2;
        *(volatile int*)&sready[3] = 3;
    }

    int t = 1;
    #pragma unroll 1
    for (int c = 0; c < NCH; c++) {
        int slot = c & 7;
        while (*(volatile int*)&dflag[slot] != c) {}
        asm volatile("" ::: "memory");
        int q_0 = ringq[slot][0][lane];
        int q_1 = ringq[slot][1][lane];
        int q_2 = ringq[slot][2][lane];
        int q_3 = ringq[slot][3][lane];
        int q_4 = ringq[slot][4][lane];
        int q_5 = ringq[slot][5][lane];

        int packed = 0;
        CHS1(0) CHS1(1) CHS1(2) CHS1(3) CHS1(4) CHS1(5)
        if (lane < 6 && t + lane < 1024) wind[ibase + t + lane] = packed;

        int nc = c + DLA;
        if (nc < NCH) {
            int nb = ind < 960 ? ind : 960;
            int ns = nc & 7;
            if (lane == 0) sbase[ns] = nb;
            asm volatile("s_waitcnt lgkmcnt(0)" ::: "memory");
            if (lane == 0) *(volatile int*)&sready[ns] = nc;
            b0 = b1; b1 = b2; b2 = b3; b3 = nb;
        } else {
            b0 = b1; b1 = b2; b2 = b3;
        }
        t += 6;
    }
}

/* ---------------- K3: per-row hinge-loss partial + z_q gather + idx emit ------ */
__global__ __launch_bounds__(256) void k3_loss_zq(const float* __restrict__ e,
                                                  const int* __restrict__ wind,
                                                  const float* __restrict__ book,
                                                  float* __restrict__ part,
                                                  float* __restrict__ out) {
    int rIdx = blockIdx.x, tid = threadIdx.x;
    int ind = wind[rIdx];
    const float* er = e + (size_t)rIdx * NPAD;
    float eind = er[ind];
    float p = 0.0f;
    for (int n = tid; n < NCOL; n += 256) {
        float v = eind - er[n] + EPSC;
        p += v > 0.0f ? v : 0.0f;
    }
    __shared__ float sd[256];
    sd[tid] = p; __syncthreads();
    for (int s = 128; s > 0; s >>= 1) { if (tid < s) sd[tid] += sd[tid + s]; __syncthreads(); }
    if (tid == 0) { part[rIdx] = sd[0]; out[OUT_IDX + rIdx] = (float)ind; }
    out[(size_t)rIdx * 256 + tid] = book[(size_t)ind * EDIM + tid];   /* z_q */
}

/* ---------------- K4: final loss reduce + v ---------------- */
__global__ __launch_bounds__(256) void k4_final(const float* __restrict__ part,
                                                const int* __restrict__ wind,
                                                float* __restrict__ out) {
    int tid = threadIdx.x;
    float s = 0.0f;
    for (int i = tid; i < NROW; i += 256) s += part[i];
    __shared__ float sd[256];
    sd[tid] = s; __syncthreads();
    for (int st = 128; st > 0; st >>= 1) { if (tid < st) sd[tid] += sd[tid + st]; __syncthreads(); }
    if (tid == 0) {
        int mn = wind[0], mx = wind[TT - 1];
        for (int b = 1; b < BB; b++) {
            mn = min(mn, wind[(size_t)b * TT]);
            mx = max(mx, wind[(size_t)b * TT + TT - 1]);
        }
        out[OUT_LOSS] = 1.25f * sd[0] / ((float)NROW * (float)NCOL);
        out[OUT_V] = (float)(mx - mn);
    }
}

extern "C" void kernel_launch(void* const* d_in, const int* in_sizes, int n_in,
                              void* d_out, int out_size, void* d_ws, size_t ws_size,
                              hipStream_t stream) {
    const float* z    = (const float*)d_in[0];
    const float* book = (const float*)d_in[1];
    char* ws = (char*)d_ws;
    unsigned short* zb = (unsigned short*)(ws + WS_ZB);
    unsigned short* bb = (unsigned short*)(ws + WS_BBF);
    float* bsq  = (float*)(ws + WS_BSQ);
    float* e    = (float*)(ws + WS_E);
    int*   wind = (int*)(ws + WS_IND);
    float* part = (float*)(ws + WS_PART);
    float* out  = (float*)d_out;

    hipLaunchKernelGGL(k0_prep,    dim3(4096 + 1152), dim3(256), 0, stream, z, book, zb, bb, bsq);
    hipLaunchKernelGGL(k1_gemm,    dim3(128, 9),      dim3(256), 0, stream, zb, bb, bsq, e);
    hipLaunchKernelGGL(k2_scan,    dim3(16),          dim3(512), 0, stream, z, book, bsq, e, wind);
    hipLaunchKernelGGL(k3_loss_zq, dim3(16384),       dim3(256), 0, stream, e, wind, book, part, out);
    hipLaunchKernelGGL(k4_final,   dim3(1),           dim3(256), 0, stream, part, wind, out);
}

// Round 12
// 249.342 us; speedup vs baseline: 1.0701x; 1.0528x over previous
//
#include <hip/hip_runtime.h>

#define N_E   1024
#define EDIM  256
#define BB    16
#define TT    1024
#define NROW  (BB*TT)        /* 16384 */
#define NCOL  1025
#define NPAD  1152           /* row-major e row stride */
#define PERS  (0.1f/1024.0f)
#define EPSC  (1e-6f/1024.0f)

/* d_out layout (float32): z_q [0,4194304) | loss 4194304 | ind [4194305,+16384) | v 4210689 */
#define OUT_LOSS 4194304
#define OUT_IDX  4194305
#define OUT_V    4210689

/* ws layout (bytes) */
#define WS_ZB   0ull                               /* 16384*256*2  = 8388608  */
#define WS_BBF  8388608ull                         /* 1152*256*2   = 589824   */
#define WS_BSQ  8978432ull                         /* 1152*4       = 4608     */
#define WS_E    8983552ull                         /* 16384*1152*4 = 75497472 */
#define WS_IND  84481024ull                        /* 16384*4                 */
#define WS_PART 84546560ull                        /* 16384*4                 */

typedef __attribute__((ext_vector_type(8))) short short8;
typedef __attribute__((ext_vector_type(4))) float floatx4;

__device__ __forceinline__ unsigned short f2bf(float f) {
    unsigned int u = __float_as_uint(f);
    u = (u + 0x7fffu + ((u >> 16) & 1u)) >> 16;   /* RNE */
    return (unsigned short)u;
}

__device__ __forceinline__ float gload_f32(const float* p) {
    float r;
    asm volatile("global_load_dword %0, %1, off" : "=v"(r) : "v"(p));
    return r;
}

/* ---------------- K0: convert z/book -> bf16, compute bsq (fp32) ---------------- */
__global__ __launch_bounds__(256) void k0_prep(const float* __restrict__ z,
                                               const float* __restrict__ book,
                                               unsigned short* __restrict__ zb,
                                               unsigned short* __restrict__ bb,
                                               float* __restrict__ bsq) {
    int bx = blockIdx.x, tid = threadIdx.x;
    if (bx < 4096) {                     /* z: 4096 blocks * 256 thr * 4 floats */
        float4 v = ((const float4*)z)[bx * 256 + tid];
        size_t o = ((size_t)bx * 256 + tid) * 4;
        zb[o + 0] = f2bf(v.x); zb[o + 1] = f2bf(v.y);
        zb[o + 2] = f2bf(v.z); zb[o + 3] = f2bf(v.w);
    } else {                             /* book rows, padded to 1152 with zeros */
        int row = bx - 4096;             /* 0..1151 */
        float v = (row < NCOL) ? book[(size_t)row * EDIM + tid] : 0.0f;
        bb[(size_t)row * EDIM + tid] = f2bf(v);
        __shared__ float sd[256];
        sd[tid] = v * v;
        __syncthreads();
        for (int s = 128; s > 0; s >>= 1) { if (tid < s) sd[tid] += sd[tid + s]; __syncthreads(); }
        if (tid == 0) bsq[row] = sd[0];
    }
}

/* ---------------- K1: e[r][n] = bsq[n] - 2 * dot(z[r], book[n])  (bf16 MFMA) ----
   Epilogue REWORKED (r11 post-mortem): the old store wrote MFMA fragments in
   frag layout -- each instruction = 4 rows x 16 cols = four 64B runs 4.6KB
   apart, i.e. quarter-cache-line scatter on all 75MB of e (write-allocate
   RMW at HBM). Now: stage each 64-row half-tile in LDS (values bit-identical:
   fmaf(-2,acc,bsql)), then cooperatively store 512B-contiguous float4 runs. */
__global__ __launch_bounds__(256) void k1_gemm(const unsigned short* __restrict__ zb,
                                               const unsigned short* __restrict__ bb,
                                               const float* __restrict__ bsq,
                                               float* __restrict__ e) {
    int tid = threadIdx.x;
    int lane = tid & 63, w = tid >> 6;
    int mBase = blockIdx.x * 128 + (w >> 1) * 64;
    int nBase = blockIdx.y * 128 + (w & 1) * 64;
    int r = lane & 15, q = lane >> 4;

    floatx4 acc[4][4];
    #pragma unroll
    for (int i = 0; i < 4; i++)
        #pragma unroll
        for (int j = 0; j < 4; j++) acc[i][j] = (floatx4){0.f, 0.f, 0.f, 0.f};

    const short8* A = (const short8*)zb;   /* row stride 256 bf16 = 32 short8 */
    const short8* Bm = (const short8*)bb;

    #pragma unroll
    for (int ks = 0; ks < 8; ks++) {
        int k8 = ks * 4 + q;
        short8 a[4], b[4];
        #pragma unroll
        for (int i = 0; i < 4; i++) a[i] = A[(size_t)(mBase + i * 16 + r) * 32 + k8];
        #pragma unroll
        for (int j = 0; j < 4; j++) b[j] = Bm[(size_t)(nBase + j * 16 + r) * 32 + k8];
        #pragma unroll
        for (int i = 0; i < 4; i++)
            #pragma unroll
            for (int j = 0; j < 4; j++)
                acc[i][j] = __builtin_amdgcn_mfma_f32_16x16x32_bf16(a[i], b[j], acc[i][j], 0, 0, 0);
    }

    float bsql[4];
    #pragma unroll
    for (int j = 0; j < 4; j++) bsql[j] = bsq[nBase + j * 16 + r];

    __shared__ float st[64][132];          /* 33792 B staging, two row-half passes */
    int mB = blockIdx.x * 128, nB = blockIdx.y * 128;
    int cw = (w & 1) * 64;

    /* pass A: waves 0,1 stage rows 0..63 of the block tile */
    if (w < 2) {
        #pragma unroll
        for (int i = 0; i < 4; i++)
            #pragma unroll
            for (int rr = 0; rr < 4; rr++) {
                int Rq = i * 16 + q * 4 + rr;
                #pragma unroll
                for (int j = 0; j < 4; j++)
                    st[Rq][cw + j * 16 + r] = fmaf(-2.0f, acc[i][j][rr], bsql[j]);
            }
    }
    __syncthreads();
    #pragma unroll
    for (int it = 0; it < 8; it++) {
        int idx = it * 1024 + tid * 4;
        int R = idx >> 7, C = idx & 127;
        *(float4*)&e[(size_t)(mB + R) * NPAD + nB + C] = *(const float4*)&st[R][C];
    }
    __syncthreads();
    /* pass B: waves 2,3 stage rows 64..127 */
    if (w >= 2) {
        #pragma unroll
        for (int i = 0; i < 4; i++)
            #pragma unroll
            for (int rr = 0; rr < 4; rr++) {
                int Rq = i * 16 + q * 4 + rr;
                #pragma unroll
                for (int j = 0; j < 4; j++)
                    st[Rq][cw + j * 16 + r] = fmaf(-2.0f, acc[i][j][rr], bsql[j]);
            }
    }
    __syncthreads();
    #pragma unroll
    for (int it = 0; it < 8; it++) {
        int idx = it * 1024 + tid * 4;
        int R = idx >> 7, C = idx & 127;
        *(float4*)&e[(size_t)(mB + 64 + R) * NPAD + nB + C] = *(const float4*)&st[R][C];
    }
}

/* ---------------- K2: serial neighbor scan (r6 structure, best measured 84.7us)
   Phase A (4 waves): fp32 argmin of d[b,0,:] reference-style.
   Phase B (wave 0): integer-scan. 32-col window, 2 rows packed per 64-lane
   load (lane = (row&1)*32 + col). Chunk = 10 rows -> 5 loads/chunk, depth-2
   pipeline -> ~15 live prefetch VGPRs (no spill).
   Drift bound: base snapshot at iter c serves chunk c+2; drift <= 29 <= 30.
   Base clamp min(ind,992) puts col 1023 on the cap lane (q forced 0 there =
   exact reference behavior at ind=1023); shfl_down width 32 keeps the col+1
   neighbor inside the row segment.
   vmcnt ledger: steady-state queue at the wait = [c+1 loads x5, store,
   c+2 loads x5, store] = 12 -> vmcnt(6) retires exactly chunk c+1's loads
   + the older store. Prologue [init store, chunk0 x5, chunk1 x5] = 11 ->
   vmcnt(5) retires store + chunk0.                                           */

#define DECLW float A0_0, A0_1, A0_2, A0_3, A0_4, A1_0, A1_1, A1_2, A1_3, A1_4; \
              int q_0, q_1, q_2, q_3, q_4;

#define LDOP(S,k) { int _t = _tb + 2*k + _g; _t = _t < 1024 ? _t : 1023; \
                    A##S##_##k = gload_f32(_pe + (size_t)_t * NPAD); }
#define LDSET(S) LDOP(S,0) LDOP(S,1) LDOP(S,2) LDOP(S,3) LDOP(S,4)

#define QCOP(S,k) { float _bv = __shfl_down(A##S##_##k, 1, 32); \
                    int _qv = (int)((_bv - A##S##_##k) * QS); \
                    q_##k = _capn ? 0 : _qv; }
#define QCSET(S) QCOP(S,0) QCOP(S,1) QCOP(S,2) QCOP(S,3) QCOP(S,4)

/* chain step: row j of chunk, q register k=j>>1, half h=(j&1)*32 */
#define CHS(j,k,h) { int _rel = ind - cbc; \
                     int _qv = __builtin_amdgcn_readlane(q_##k, _rel + h); \
                     bool _stay = (kk <= _qv); \
                     int _ip1 = ind + 1; _ip1 = _ip1 < 1023 ? _ip1 : 1023; \
                     ind = _stay ? ind : _ip1; \
                     kk  = _stay ? kk + 1 : 0; \
                     packed = (lane == j) ? ind : packed; }
#define CHAIN CHS(0,0,0) CHS(1,0,32) CHS(2,1,0) CHS(3,1,32) CHS(4,2,0) \
              CHS(5,2,32) CHS(6,3,0) CHS(7,3,32) CHS(8,4,0) CHS(9,4,32)

#define ITERX(SI, SQ) { \
    int cbI = ind < 992 ? ind : 992;                 /* base, chunk c+2 */ \
    { const float* _pe = eb + cbI + _cl; int _tb = t + 20; LDSET(SI) } \
    __builtin_amdgcn_sched_barrier(0); \
    int packed = 0; \
    CHAIN \
    if (lane < 10 && t + lane < 1024) wind[ibase + t + lane] = packed; \
    __builtin_amdgcn_sched_barrier(0); \
    asm volatile("s_waitcnt vmcnt(6)" ::: "memory"); /* chunk c+1 loads done */ \
    __builtin_amdgcn_sched_barrier(0); \
    { bool _capn = (cbn + _cl == 1023); QCSET(SQ) } \
    cbc = cbn; cbn = cbI; \
    t += 10; }

__global__ __launch_bounds__(256, 1) void k2_scan(const float* __restrict__ z,
                                                  const float* __restrict__ book,
                                                  const float* __restrict__ bsq,
                                                  const float* __restrict__ e,
                                                  int* __restrict__ wind) {
    __shared__ float sb[4]; __shared__ int si[4];

    int b = blockIdx.x, tid = threadIdx.x;
    int lane = tid & 63, w = tid >> 6;

    const float4* zr = (const float4*)(z + (size_t)b * TT * EDIM);  /* t=0 row */
    float4 zv = zr[lane];
    float s = zv.x * zv.x + zv.y * zv.y + zv.z * zv.z + zv.w * zv.w;
    #pragma unroll
    for (int off = 32; off; off >>= 1) s += __shfl_xor(s, off, 64);
    float zsq = s;

    float best = 3.4e38f; int bidx = 0;
    for (int wi = w; wi < 17; wi += 4) {
        int n = wi * 64 + lane;
        if (n < NCOL) {
            const float4* br = (const float4*)(book + (size_t)n * EDIM);
            float c0 = 0.f, c1 = 0.f, c2 = 0.f, c3 = 0.f;
            #pragma unroll 8
            for (int k = 0; k < 64; k++) {
                float4 bo = br[k]; float4 za = zr[k];
                c0 = fmaf(za.x, bo.x, c0); c1 = fmaf(za.y, bo.y, c1);
                c2 = fmaf(za.z, bo.z, c2); c3 = fmaf(za.w, bo.w, c3);
            }
            float cr = (c0 + c1) + (c2 + c3);
            float d0 = (zsq + bsq[n]) - 2.0f * cr;     /* reference-style formation */
            if (d0 < best || (d0 == best && n < bidx)) { best = d0; bidx = n; }
        }
    }
    #pragma unroll
    for (int off = 32; off; off >>= 1) {
        float ob = __shfl_xor(best, off, 64);
        int   oi = __shfl_xor(bidx, off, 64);
        if (ob < best || (ob == best && oi < bidx)) { best = ob; bidx = oi; }
    }
    if (lane == 0) { sb[w] = best; si[w] = bidx; }
    __syncthreads();
    if (w != 0) return;

    best = sb[0]; bidx = si[0];
    for (int i = 1; i < 4; i++) {
        float vv = sb[i]; int ii = si[i];
        if (vv < best || (vv == best && ii < bidx)) { best = vv; bidx = ii; }
    }

    int ind = min(bidx, N_E - 1);
    int kk = 0;                              /* coe = kk * PERS */
    size_t ibase = (size_t)b * TT;
    if (lane == 0) wind[ibase] = ind;

    const float* eb = e + (size_t)b * TT * NPAD;
    const float QS = 1.0f / PERS;            /* 10240 */

    int _g = lane >> 5;                      /* row-in-pair */
    int _cl = lane & 31;                     /* col-in-window */

    DECLW                                    /* A{0,1}_{0..4}, q_{0..4} */

    int cbc = ind < 992 ? ind : 992;         /* base, chunk 0 */
    int cbn = cbc;                           /* base, chunk 1 (drift<=19 ok) */
    /* prologue: issue chunks 0 (rows 1-10) and 1 (rows 11-20) */
    { const float* _pe = eb + cbc + _cl; int _tb = 1;  LDSET(0) }
    { const float* _pe = eb + cbn + _cl; int _tb = 11; LDSET(1) }
    asm volatile("s_waitcnt vmcnt(5)" ::: "memory");   /* chunk 0 (+init store) done */
    __builtin_amdgcn_sched_barrier(0);
    { bool _capn = (cbc + _cl == 1023); QCSET(0) }     /* q for chunk 0 */

    int t = 1;
    #pragma unroll 1
    for (int cc = 0; cc < 52; cc++) {        /* 104 chunks of 10 rows (t>=1024 guarded) */
        ITERX(0, 1)
        ITERX(1, 0)
    }
}

/* ---------------- K3: per-row hinge-loss partial + z_q gather + idx emit ------ */
__global__ __launch_bounds__(256) void k3_loss_zq(const float* __restrict__ e,
                                                  const int* __restrict__ wind,
                                                  const float* __restrict__ book,
                                                  float* __restrict__ part,
                                                  float* __restrict__ out) {
    int rIdx = blockIdx.x, tid = threadIdx.x;
    int ind = wind[rIdx];
    const float* er = e + (size_t)rIdx * NPAD;
    float eind = er[ind];
    float p = 0.0f;
    for (int n = tid; n < NCOL; n += 256) {
        float v = eind - er[n] + EPSC;
        p += v > 0.0f ? v : 0.0f;
    }
    __shared__ float sd[256];
    sd[tid] = p; __syncthreads();
    for (int s = 128; s > 0; s >>= 1) { if (tid < s) sd[tid] += sd[tid + s]; __syncthreads(); }
    if (tid == 0) { part[rIdx] = sd[0]; out[OUT_IDX + rIdx] = (float)ind; }
    out[(size_t)rIdx * 256 + tid] = book[(size_t)ind * EDIM + tid];   /* z_q */
}

/* ---------------- K4: final loss reduce + v ---------------- */
__global__ __launch_bounds__(256) void k4_final(const float* __restrict__ part,
                                                const int* __restrict__ wind,
                                                float* __restrict__ out) {
    int tid = threadIdx.x;
    float s = 0.0f;
    for (int i = tid; i < NROW; i += 256) s += part[i];
    __shared__ float sd[256];
    sd[tid] = s; __syncthreads();
    for (int st = 128; st > 0; st >>= 1) { if (tid < st) sd[tid] += sd[tid + st]; __syncthreads(); }
    if (tid == 0) {
        int mn = wind[0], mx = wind[TT - 1];
        for (int b = 1; b < BB; b++) {
            mn = min(mn, wind[(size_t)b * TT]);
            mx = max(mx, wind[(size_t)b * TT + TT - 1]);
        }
        out[OUT_LOSS] = 1.25f * sd[0] / ((float)NROW * (float)NCOL);
        out[OUT_V] = (float)(mx - mn);
    }
}

extern "C" void kernel_launch(void* const* d_in, const int* in_sizes, int n_in,
                              void* d_out, int out_size, void* d_ws, size_t ws_size,
                              hipStream_t stream) {
    const float* z    = (const float*)d_in[0];
    const float* book = (const float*)d_in[1];
    char* ws = (char*)d_ws;
    unsigned short* zb = (unsigned short*)(ws + WS_ZB);
    unsigned short* bb = (unsigned short*)(ws + WS_BBF);
    float* bsq  = (float*)(ws + WS_BSQ);
    float* e    = (float*)(ws + WS_E);
    int*   wind = (int*)(ws + WS_IND);
    float* part = (float*)(ws + WS_PART);
    float* out  = (float*)d_out;

    hipLaunchKernelGGL(k0_prep,    dim3(4096 + 1152), dim3(256), 0, stream, z, book, zb, bb, bsq);
    hipLaunchKernelGGL(k1_gemm,    dim3(128, 9),      dim3(256), 0, stream, zb, bb, bsq, e);
    hipLaunchKernelGGL(k2_scan,    dim3(16),          dim3(256), 0, stream, z, book, bsq, e, wind);
    hipLaunchKernelGGL(k3_loss_zq, dim3(16384),       dim3(256), 0, stream, e, wind, book, part, out);
    hipLaunchKernelGGL(k4_final,   dim3(1),           dim3(256), 0, stream, part, wind, out);
}